// Round 9
// baseline (361.205 us; speedup 1.0000x reference)
//
#include <hip/hip_runtime.h>
#include <hip/hip_bf16.h>

typedef _Float16 f16x8 __attribute__((ext_vector_type(8)));
typedef _Float16 f16x4 __attribute__((ext_vector_type(4)));
typedef float f32x4 __attribute__((ext_vector_type(4)));

typedef __attribute__((address_space(1))) void GV;
typedef __attribute__((address_space(3))) void LV;

__device__ inline void async16(void* lds, const void* g) {
    __builtin_amdgcn_global_load_lds((GV*)g, (LV*)lds, 16, 0, 0);
}

// ---------------- fused cast f32 -> f16 for all 7 inputs ----------------
__global__ __launch_bounds__(256) void cast_all(
    const float* __restrict__ q, const float* __restrict__ k, const float* __restrict__ v,
    const float* __restrict__ wq, const float* __restrict__ wk,
    const float* __restrict__ wv, const float* __restrict__ wo, _Float16* __restrict__ ws)
{
    const long M1 = 1048576;
    const long tot = 6291456;  // total float4s
    for (long idx = (long)blockIdx.x * 256 + threadIdx.x; idx < tot;
         idx += (long)gridDim.x * 256) {
        const float* src; long local; long doff;
        if (idx < 1572864) {                    // q,k,v: 512K f4 each
            int seg = (int)(idx >> 19);
            src = seg == 0 ? q : (seg == 1 ? k : v);
            local = idx & 524287; doff = (long)seg * 2 * M1;
        } else if (idx < 5767168) {             // wq, wk: 2M f4 each
            int seg = (int)((idx - 1572864) >> 21);
            src = seg == 0 ? wq : wk;
            local = (idx - 1572864) & 2097151; doff = (6 + 8 * (long)seg) * M1;
        } else {                                 // wv, wo: 256K f4 each
            int seg = (int)((idx - 5767168) >> 18);
            src = seg == 0 ? wv : wo;
            local = (idx - 5767168) & 262143; doff = (22 + (long)seg) * M1;
        }
        float4 val = ((const float4*)src)[local];
        f16x4 o;
        o[0] = (_Float16)val.x; o[1] = (_Float16)val.y;
        o[2] = (_Float16)val.z; o[3] = (_Float16)val.w;
        *(f16x4*)&ws[doff + 4 * local] = o;
    }
}

// ---------------- V transpose: in [b][s][e] -> out [b][e][s] ----------------
__global__ __launch_bounds__(256) void transpose_v(const _Float16* __restrict__ in,
                                                   _Float16* __restrict__ out) {
    __shared__ _Float16 tile[64][66];
    int b = blockIdx.z;
    long base = (long)b * 1048576;
    int s0 = blockIdx.x * 64, e0 = blockIdx.y * 64;
    int tc = threadIdx.x & 63, tr = threadIdx.x >> 6;
    #pragma unroll
    for (int rr = 0; rr < 64; rr += 4)
        tile[tr + rr][tc] = in[base + (long)(s0 + tr + rr) * 1024 + e0 + tc];
    __syncthreads();
    #pragma unroll
    for (int rr = 0; rr < 64; rr += 4)
        out[base + (long)(e0 + tr + rr) * 1024 + s0 + tc] = tile[tc][tr + rr];
}

// ---------------- batched GEMM: C = A @ B^T, f32 accum ----------------
// RB = row-fragments per wave (tile M = RB*32). XS: flat-grid XCD-chunk swizzle.
// omode: 0 = f16 row-major, 1 = f32 row-major,
//        2 = z<16 -> MFMA-fragment-blocked f16 into Qblk/Kblk (see attn),
//            z==16 -> f16 row-major (V) via coff.
// Blocked layout: elem (i,b,h,t,d) at (i*2+b)*1M + h*131072 + (t>>4)*2048
//                 + (d>>5 [kk])*512 + (t&15)*32 + ((d>>3)&3 [lgd])*8 + (d&7).
template<int RB, int XS, int OMODE>
__global__ __launch_bounds__(256) void gemm_bt(
    const _Float16* __restrict__ A0, const _Float16* __restrict__ B0, void* __restrict__ C0,
    int K, int lda, int ldb, int ldc,
    int az_div, long sa_hi, long sa_lo, long sb,
    int cz_div, long sc_hi, long sc_lo)
{
    __shared__ _Float16 As[RB * 32 * 64];
    __shared__ _Float16 Bs[128 * 64];
    int bx, by, bz;
    if (XS) {
        int p = blockIdx.x;
        int xcd = p & 7, s = p >> 3;
        int c, within;
        if (s < 256) { c = xcd + 8 * (s >> 6); within = s & 63; }
        else         { c = 32 + (xcd >> 2); within = (xcd & 3) * 16 + (s - 256); }
        bz = c >> 1;
        by = (c & 1) * 8 + (within >> 3);
        bx = within & 7;
    } else { bx = blockIdx.x; by = blockIdx.y; bz = blockIdx.z; }
    int z = bz;
    const _Float16* A = A0 + (long)(z / az_div) * sa_hi + (long)(z % az_div) * sa_lo;
    const _Float16* B = B0 + (long)z * sb;
    long coff = (long)(z / cz_div) * sc_hi + (long)(z % cz_div) * sc_lo;
    int rowbase = by * (RB * 32), colbase = bx * 128;
    int t = threadIdx.x, wave = t >> 6, lane = t & 63;
    int l15 = lane & 15, lg = lane >> 4;
    int srow = t >> 3, scol = (t & 7) * 8;
    int wm = wave >> 1, wn = wave & 1;
    f32x4 acc[RB][4] = {};
    for (int k0 = 0; k0 < K; k0 += 64) {
        #pragma unroll
        for (int ii = 0; ii < RB; ii++) {
            int r = srow + ii * 32;
            async16(&As[r * 64 + scol], A + (long)(rowbase + r) * lda + k0 + scol);
        }
        #pragma unroll
        for (int ii = 0; ii < 4; ii++) {
            int r = srow + ii * 32;
            async16(&Bs[r * 64 + scol], B + (long)(colbase + r) * ldb + k0 + scol);
        }
        __syncthreads();
        #pragma unroll
        for (int ks = 0; ks < 2; ks++) {
            f16x8 af[RB], bfr[4];
            #pragma unroll
            for (int m = 0; m < RB; m++)
                af[m] = *(const f16x8*)&As[(wm * (RB * 16) + m * 16 + l15) * 64 + ks * 32 + lg * 8];
            #pragma unroll
            for (int n = 0; n < 4; n++)
                bfr[n] = *(const f16x8*)&Bs[(wn * 64 + n * 16 + l15) * 64 + ks * 32 + lg * 8];
            #pragma unroll
            for (int m = 0; m < RB; m++)
                #pragma unroll
                for (int n = 0; n < 4; n++)
                    acc[m][n] = __builtin_amdgcn_mfma_f32_16x16x32_f16(af[m], bfr[n], acc[m][n], 0, 0, 0);
        }
        __syncthreads();
    }
    if (OMODE == 2 && z < 16) {
        // blocked Q/K write. i = z&7; K region offset 16M for z>=8.
        long qk_off = (z < 8) ? 0L : 16L * 1048576;
        int i_h = z & 7;
        int h = bx;  // colbase = bx*128, full head per bx
        #pragma unroll
        for (int n = 0; n < 4; n++) {
            int kk = wn * 2 + (n >> 1);
            int lgd = (n & 1) * 2 + (l15 >> 3);
            int e = l15 & 7;
            long colpart = kk * 512 + lgd * 8 + e;
            #pragma unroll
            for (int m = 0; m < RB; m++) {
                #pragma unroll
                for (int r = 0; r < 4; r++) {
                    int row = rowbase + wm * (RB * 16) + m * 16 + lg * 4 + r;
                    int b = row >> 10;
                    int tt = (row >> 4) & 63;
                    int tin = lg * 4 + r;   // == row & 15
                    long dst = qk_off + (long)(i_h * 2 + b) * 1048576
                             + h * 131072 + tt * 2048 + tin * 32 + colpart;
                    ((_Float16*)C0)[dst] = (_Float16)acc[m][n][r];
                }
            }
        }
    } else {
        #pragma unroll
        for (int m = 0; m < RB; m++) {
            int row = rowbase + wm * (RB * 16) + m * 16 + lg * 4;
            #pragma unroll
            for (int n = 0; n < 4; n++) {
                int col = colbase + wn * 64 + n * 16 + l15;
                #pragma unroll
                for (int r = 0; r < 4; r++) {
                    long idx = coff + (long)(row + r) * ldc + col;
                    if (OMODE == 1) ((float*)C0)[idx] = acc[m][n][r];
                    else ((_Float16*)C0)[idx] = (_Float16)acc[m][n][r];
                }
            }
        }
    }
}

// ---------------- fused attn v9: register-direct on blocked Q/K ----------------
// 1024 blocks (XCD-swizzled), 512 threads = 8 waves; block = 16 t-rows (tile tt)
// x 1024 s of one (b,h); wave sw owns s-cols [sw*128, sw*128+128) = 8 col-tiles.
// Q/K are in MFMA-fragment-blocked layout: each 16x32 fragment = contiguous
// 1KB; lane reads 16B at base + (l15*4+lg)*16 -> perfectly coalesced, no LDS,
// no barriers in the hot loop. Softmax: no max-shift (scores bounded);
// one cross-wave sum reduction per head i.
__global__ __launch_bounds__(512, 3) void attn_fused(
    const _Float16* __restrict__ Qblk, const _Float16* __restrict__ Kblk,
    float* __restrict__ attn_out, _Float16* __restrict__ Pbar)
{
    __shared__ float red[8][16];
    int id = blockIdx.x;
    int orig = (id & 7) * 128 + (id >> 3);   // XCD k owns bh {2k,2k+1}
    int tt = orig & 63;
    int bh = orig >> 6, h = bh & 7, b = bh >> 3;
    int tid = threadIdx.x, wave = tid >> 6, lane = tid & 63;
    int l15 = lane & 15, lg = lane >> 4;
    int sw = wave;
    int lq = l15 * 4 + lg;                    // lane index within 512-elem fragment block
    const float scale = 0.088388347648318447f;  // 1/sqrt(128)
    const long istride = 2097152;             // (i+1,b,..) - (i,b,..) in f16 elems
    float acc[8][4] = {};

    const _Float16* qb = Qblk + ((((long)b * 8 + h) * 64 + tt) * 4) * 512 + lq * 8;
    const _Float16* kb = Kblk + (((long)b * 8 + h) * 64 * 4) * 512
                       + (sw * 8) * 2048 + lq * 8;

    #pragma unroll 1
    for (int i = 0; i < 8; i++) {
        f16x8 aq[4];
        #pragma unroll
        for (int kk = 0; kk < 4; kk++)
            aq[kk] = *(const f16x8*)(qb + (long)i * istride + kk * 512);
        const _Float16* kbi = kb + (long)i * istride;
        float s[8][4];
        float rs[4] = {0.f, 0.f, 0.f, 0.f};
        #pragma unroll
        for (int ct = 0; ct < 8; ct++) {
            const _Float16* kt = kbi + ct * 2048;
            f32x4 sv = {0.f, 0.f, 0.f, 0.f};
            #pragma unroll
            for (int kk = 0; kk < 4; kk++) {
                f16x8 bk = *(const f16x8*)(kt + kk * 512);
                sv = __builtin_amdgcn_mfma_f32_16x16x32_f16(aq[kk], bk, sv, 0, 0, 0);
            }
            #pragma unroll
            for (int r = 0; r < 4; r++) {
                float e = __expf(sv[r] * scale);
                s[ct][r] = e;
                rs[r] += e;
            }
        }
        // row-sum reduce: across l15 lanes, then across all 8 waves
        #pragma unroll
        for (int off = 1; off < 16; off <<= 1)
            #pragma unroll
            for (int r = 0; r < 4; r++) rs[r] += __shfl_xor(rs[r], off, 64);
        if (l15 == 0) {
            #pragma unroll
            for (int r = 0; r < 4; r++) red[wave][lg * 4 + r] = rs[r];
        }
        __syncthreads();
        #pragma unroll
        for (int r = 0; r < 4; r++) {
            int row = lg * 4 + r;
            float tot = red[0][row] + red[1][row] + red[2][row] + red[3][row]
                      + red[4][row] + red[5][row] + red[6][row] + red[7][row];
            float rinv = 0.125f / tot;
            #pragma unroll
            for (int ct = 0; ct < 8; ct++) acc[ct][r] += s[ct][r] * rinv;
        }
        __syncthreads();   // red reads done before next i's writes
    }

    long rbase = ((long)(bh * 1024 + tt * 16)) * 1024;
    #pragma unroll
    for (int ct = 0; ct < 8; ct++) {
        int scol = sw * 128 + ct * 16 + l15;
        #pragma unroll
        for (int r = 0; r < 4; r++) {
            long idx = rbase + (long)(lg * 4 + r) * 1024 + scol;
            attn_out[idx] = acc[ct][r];
            Pbar[idx] = (_Float16)acc[ct][r];
        }
    }
}

extern "C" void kernel_launch(void* const* d_in, const int* in_sizes, int n_in,
                              void* d_out, int out_size, void* d_ws, size_t ws_size,
                              hipStream_t stream) {
    const long M1 = 1048576;
    _Float16* ws = (_Float16*)d_ws;
    _Float16* q16  = ws;             // 2M elts (query; key at +2M, value at +4M)
    _Float16* wq16 = ws + 6 * M1;    // 8M (Wk at +8M, Wv at +16M)
    _Float16* wo16 = ws + 23 * M1;   // 1M
    _Float16* Qbuf = ws + 24 * M1;   // 16M blocked Q (Kblk at +16M, Vbuf at +32M)
    _Float16* Vbuf = ws + 56 * M1;   // 2M  (== Qbuf + 32M, row-major)
    _Float16* Vt   = ws + 58 * M1;   // 2M
    _Float16* Pb   = ws + 60 * M1;   // 16M
    _Float16* Hbar = ws + 76 * M1;   // 2M
    float* out = (float*)d_out;
    float* attn_out = out + 2 * M1;

    // all 7 casts in one dispatch
    cast_all<<<2048, 256, 0, stream>>>(
        (const float*)d_in[0], (const float*)d_in[1], (const float*)d_in[2],
        (const float*)d_in[3], (const float*)d_in[4], (const float*)d_in[5],
        (const float*)d_in[6], ws);

    // Projections, one dispatch (XCD-chunk swizzled flat grid):
    // z=0..7 Q_i (blocked), z=8..15 K_i (blocked), z=16 V (row-major).
    gemm_bt<4, 1, 2><<<2176, 256, 0, stream>>>(
        q16, wq16, Qbuf, 1024, 1024, 1024, 1024,
        /*az*/ 8, 2 * M1, 0, /*sb*/ M1,
        /*cz*/ 16, 32 * M1, 2 * M1);
    // V transpose -> Vt[b][e][s]
    transpose_v<<<dim3(16, 16, 2), 256, 0, stream>>>(Vbuf, Vt);
    // fused scores+softmax+mean_i -> attention (f32) + Pbar (f16)
    attn_fused<<<1024, 512, 0, stream>>>(Qbuf, Qbuf + 16 * M1, attn_out, Pb);
    // PV: head[b][t][h*128+n] = sum_s Pbar[(b,h)][t][s] * Vt[b][h*128+n][s]
    gemm_bt<2, 0, 0><<<dim3(1, 16, 16), 256, 0, stream>>>(
        Pb, Vt, Hbar, 1024, 1024, 1024, 1024,
        /*az*/ 16, 0, M1, /*sb*/ M1 / 8,
        /*cz*/ 8, M1, 128);
    // out = head_mean @ Wo^T  (f32 out)
    gemm_bt<2, 0, 1><<<dim3(8, 32, 1), 256, 0, stream>>>(
        Hbar, wo16, out, 1024, 1024, 1024, 1024,
        1, 0, 0, 0, 1, 0, 0);
}

// Round 10
// 325.380 us; speedup vs baseline: 1.1101x; 1.1101x over previous
//
#include <hip/hip_runtime.h>
#include <hip/hip_bf16.h>

typedef _Float16 f16x8 __attribute__((ext_vector_type(8)));
typedef _Float16 f16x4 __attribute__((ext_vector_type(4)));
typedef float f32x4 __attribute__((ext_vector_type(4)));

typedef __attribute__((address_space(1))) void GV;
typedef __attribute__((address_space(3))) void LV;

__device__ inline void async16(void* lds, const void* g) {
    __builtin_amdgcn_global_load_lds((GV*)g, (LV*)lds, 16, 0, 0);
}

// ---------------- fused cast f32 -> f16 for all 7 inputs ----------------
__global__ __launch_bounds__(256) void cast_all(
    const float* __restrict__ q, const float* __restrict__ k, const float* __restrict__ v,
    const float* __restrict__ wq, const float* __restrict__ wk,
    const float* __restrict__ wv, const float* __restrict__ wo, _Float16* __restrict__ ws)
{
    const long M1 = 1048576;
    const long tot = 6291456;  // total float4s
    for (long idx = (long)blockIdx.x * 256 + threadIdx.x; idx < tot;
         idx += (long)gridDim.x * 256) {
        const float* src; long local; long doff;
        if (idx < 1572864) {                    // q,k,v: 512K f4 each
            int seg = (int)(idx >> 19);
            src = seg == 0 ? q : (seg == 1 ? k : v);
            local = idx & 524287; doff = (long)seg * 2 * M1;
        } else if (idx < 5767168) {             // wq, wk: 2M f4 each
            int seg = (int)((idx - 1572864) >> 21);
            src = seg == 0 ? wq : wk;
            local = (idx - 1572864) & 2097151; doff = (6 + 8 * (long)seg) * M1;
        } else {                                 // wv, wo: 256K f4 each
            int seg = (int)((idx - 5767168) >> 18);
            src = seg == 0 ? wv : wo;
            local = (idx - 5767168) & 262143; doff = (22 + (long)seg) * M1;
        }
        float4 val = ((const float4*)src)[local];
        f16x4 o;
        o[0] = (_Float16)val.x; o[1] = (_Float16)val.y;
        o[2] = (_Float16)val.z; o[3] = (_Float16)val.w;
        *(f16x4*)&ws[doff + 4 * local] = o;
    }
}

// ---------------- V transpose: in [b][s][e] -> out [b][e][s] ----------------
__global__ __launch_bounds__(256) void transpose_v(const _Float16* __restrict__ in,
                                                   _Float16* __restrict__ out) {
    __shared__ _Float16 tile[64][66];
    int b = blockIdx.z;
    long base = (long)b * 1048576;
    int s0 = blockIdx.x * 64, e0 = blockIdx.y * 64;
    int tc = threadIdx.x & 63, tr = threadIdx.x >> 6;
    #pragma unroll
    for (int rr = 0; rr < 64; rr += 4)
        tile[tr + rr][tc] = in[base + (long)(s0 + tr + rr) * 1024 + e0 + tc];
    __syncthreads();
    #pragma unroll
    for (int rr = 0; rr < 64; rr += 4)
        out[base + (long)(e0 + tr + rr) * 1024 + s0 + tc] = tile[tc][tr + rr];
}

// ---------------- batched GEMM v2: C = A @ B^T, double-buffered staging ----------------
// RB = row-fragments per wave (tile M = RB*32). XS: flat-grid XCD-chunk swizzle.
// OMODE: 0 = f16 row-major, 1 = f32 row-major.
// Loop pattern (attn-v8-proven, 1 barrier/K-step):
//   {__syncthreads (drain stage(t); buf[(t+1)&1] reads done) -> issue stage(t+1)
//    -> compute(t)}. DMA of t+1 overlaps compute(t).
template<int RB, int XS, int OMODE>
__global__ __launch_bounds__(256) void gemm_bt(
    const _Float16* __restrict__ A0, const _Float16* __restrict__ B0, void* __restrict__ C0,
    int K, int lda, int ldb, int ldc,
    int az_div, long sa_hi, long sa_lo, long sb,
    int cz_div, long sc_hi, long sc_lo)
{
    __shared__ _Float16 As[2][RB * 32 * 64];
    __shared__ _Float16 Bs[2][128 * 64];
    int bx, by, bz;
    if (XS) {
        int p = blockIdx.x;
        int xcd = p & 7, s = p >> 3;
        int c, within;
        if (s < 256) { c = xcd + 8 * (s >> 6); within = s & 63; }
        else         { c = 32 + (xcd >> 2); within = (xcd & 3) * 16 + (s - 256); }
        bz = c >> 1;
        by = (c & 1) * 8 + (within >> 3);
        bx = within & 7;
    } else { bx = blockIdx.x; by = blockIdx.y; bz = blockIdx.z; }
    int z = bz;
    const _Float16* A = A0 + (long)(z / az_div) * sa_hi + (long)(z % az_div) * sa_lo;
    const _Float16* B = B0 + (long)z * sb;
    long coff = (long)(z / cz_div) * sc_hi + (long)(z % cz_div) * sc_lo;
    int rowbase = by * (RB * 32), colbase = bx * 128;
    int t = threadIdx.x, wave = t >> 6, lane = t & 63;
    int l15 = lane & 15, lg = lane >> 4;
    int srow = t >> 3, scol = (t & 7) * 8;
    int wm = wave >> 1, wn = wave & 1;
    f32x4 acc[RB][4] = {};
    const int nt = K >> 6;

    // prologue: stage k-step 0 into buf 0
    #pragma unroll
    for (int ii = 0; ii < RB; ii++) {
        int r = srow + ii * 32;
        async16(&As[0][r * 64 + scol], A + (long)(rowbase + r) * lda + scol);
    }
    #pragma unroll
    for (int ii = 0; ii < 4; ii++) {
        int r = srow + ii * 32;
        async16(&Bs[0][r * 64 + scol], B + (long)(colbase + r) * ldb + scol);
    }

    for (int ts = 0; ts < nt; ts++) {
        __syncthreads();   // drain stage(ts); all reads of buf[(ts+1)&1] finished
        if (ts + 1 < nt) {
            int k1 = (ts + 1) << 6;
            int p1 = (ts + 1) & 1;
            #pragma unroll
            for (int ii = 0; ii < RB; ii++) {
                int r = srow + ii * 32;
                async16(&As[p1][r * 64 + scol], A + (long)(rowbase + r) * lda + k1 + scol);
            }
            #pragma unroll
            for (int ii = 0; ii < 4; ii++) {
                int r = srow + ii * 32;
                async16(&Bs[p1][r * 64 + scol], B + (long)(colbase + r) * ldb + k1 + scol);
            }
        }
        int pc = ts & 1;
        #pragma unroll
        for (int ks = 0; ks < 2; ks++) {
            f16x8 af[RB], bfr[4];
            #pragma unroll
            for (int m = 0; m < RB; m++)
                af[m] = *(const f16x8*)&As[pc][(wm * (RB * 16) + m * 16 + l15) * 64 + ks * 32 + lg * 8];
            #pragma unroll
            for (int n = 0; n < 4; n++)
                bfr[n] = *(const f16x8*)&Bs[pc][(wn * 64 + n * 16 + l15) * 64 + ks * 32 + lg * 8];
            #pragma unroll
            for (int m = 0; m < RB; m++)
                #pragma unroll
                for (int n = 0; n < 4; n++)
                    acc[m][n] = __builtin_amdgcn_mfma_f32_16x16x32_f16(af[m], bfr[n], acc[m][n], 0, 0, 0);
        }
    }
    #pragma unroll
    for (int m = 0; m < RB; m++) {
        int row = rowbase + wm * (RB * 16) + m * 16 + lg * 4;
        #pragma unroll
        for (int n = 0; n < 4; n++) {
            int col = colbase + wn * 64 + n * 16 + l15;
            #pragma unroll
            for (int r = 0; r < 4; r++) {
                long idx = coff + (long)(row + r) * ldc + col;
                if (OMODE == 1) ((float*)C0)[idx] = acc[m][n][r];
                else ((_Float16*)C0)[idx] = (_Float16)acc[m][n][r];
            }
        }
    }
}

// ---------------- fused attn v8 (reverted champion): LDS dbuf + hoisted pointers ----------------
// 1024 blocks (XCD-swizzled), 512 threads = 8 waves; block = 16 t-rows x 1024 s
// of one (b,h). 64 linearized chunk-steps m=i*8+c; buffers alternate on c&1.
// {barrier(drain m) -> issue stage(m+1, buf^1) -> compute m}.
__global__ __launch_bounds__(512, 4) void attn_fused(
    const _Float16* __restrict__ Qbuf, const _Float16* __restrict__ Kbuf,
    float* __restrict__ attn_out, _Float16* __restrict__ Pbar)
{
    __shared__ _Float16 Kc[2][128 * 128];  // 2 x 32 KB
    __shared__ float red[8][16];
    int id = blockIdx.x;
    int orig = (id & 7) * 128 + (id >> 3);   // XCD k owns bh {2k,2k+1}
    int t0 = (orig & 63) * 16;
    int bh = orig >> 6, h = bh & 7, b = bh >> 3;
    int tid = threadIdx.x, wave = tid >> 6, lane = tid & 63;
    int l15 = lane & 15, lg = lane >> 4;
    int cw = wave >> 2, sw = wave & 3;
    int brow = cw * 64 + sw * 16 + l15;
    const float scale = 0.088388347648318447f;  // 1/sqrt(128)
    float acc[8][4] = {};

    // hoisted per-thread bases
    int srow = tid >> 4;
    int scolB = (tid & 15) << 4;
    int gcolB = scolB ^ ((srow & 7) << 4);    // inverse swizzle on global source
    int ldsoff = srow * 256 + scolB;
    const char* pk = (const char*)(Kbuf + (long)b * 1048576 + h * 128)
                     + (long)srow * 2048 + gcolB;
    const char* pq = (const char*)(Qbuf + ((long)(b * 1024 + t0 + l15)) * 1024 + h * 128)
                     + lg * 16;
    int swz = (brow & 7) << 4;
    int rdoff[4];
    #pragma unroll
    for (int kk = 0; kk < 4; kk++)
        rdoff[kk] = brow * 256 + ((kk * 64 + lg * 16) ^ swz);

    // prologue: stage step 0 into buf 0
    {
        char* lb = (char*)Kc[0] + ldsoff;
        #pragma unroll
        for (int j = 0; j < 4; j++)
            async16(lb + j * 8192, pk + (long)j * 65536);
    }

    #pragma unroll 1
    for (int i = 0; i < 8; i++) {
        f16x8 aq[4];
        #pragma unroll
        for (int kk = 0; kk < 4; kk++)
            aq[kk] = *(const f16x8*)(pq + kk * 64);
        pq += 4194304;   // next i (+2M f16)
        float s[8][4];
        float rs[4] = {0.f, 0.f, 0.f, 0.f};
        #pragma unroll
        for (int c = 0; c < 8; c++) {
            int m = i * 8 + c;
            __syncthreads();   // drain stage(m); all reads of buf[(m+1)&1] done
            pk += 262144;                   // chunk + 1
            if (c == 7) pk += 2097152;      // head boundary: total +4MB per i
            if (m < 63) {
                char* lb = (char*)Kc[(c + 1) & 1] + ldsoff;
                #pragma unroll
                for (int j = 0; j < 4; j++)
                    async16(lb + j * 8192, pk + (long)j * 65536);
            }
            const char* kc = (const char*)Kc[c & 1];
            f32x4 sv = {0.f, 0.f, 0.f, 0.f};
            #pragma unroll
            for (int kk = 0; kk < 4; kk++) {
                f16x8 bk = *(const f16x8*)(kc + rdoff[kk]);
                sv = __builtin_amdgcn_mfma_f32_16x16x32_f16(aq[kk], bk, sv, 0, 0, 0);
            }
            #pragma unroll
            for (int r = 0; r < 4; r++) {
                float e = __expf(sv[r] * scale);
                s[c][r] = e;
                rs[r] += e;
            }
        }
        // row-sum reduce: across l15 lanes, then across all 8 waves
        #pragma unroll
        for (int off = 1; off < 16; off <<= 1)
            #pragma unroll
            for (int r = 0; r < 4; r++) rs[r] += __shfl_xor(rs[r], off, 64);
        if (l15 == 0) {
            #pragma unroll
            for (int r = 0; r < 4; r++) red[wave][lg * 4 + r] = rs[r];
        }
        __syncthreads();
        #pragma unroll
        for (int r = 0; r < 4; r++) {
            int row = lg * 4 + r;
            float tot = red[0][row] + red[1][row] + red[2][row] + red[3][row]
                      + red[4][row] + red[5][row] + red[6][row] + red[7][row];
            float rinv = 0.125f / tot;
            #pragma unroll
            for (int c = 0; c < 8; c++) acc[c][r] += s[c][r] * rinv;
        }
        __syncthreads();   // red reads done before next i's writes
    }

    long rbase = ((long)(bh * 1024 + t0)) * 1024;
    #pragma unroll
    for (int c = 0; c < 8; c++) {
        int scol = c * 128 + cw * 64 + sw * 16 + l15;
        #pragma unroll
        for (int r = 0; r < 4; r++) {
            long idx = rbase + (long)(lg * 4 + r) * 1024 + scol;
            attn_out[idx] = acc[c][r];
            Pbar[idx] = (_Float16)acc[c][r];
        }
    }
}

extern "C" void kernel_launch(void* const* d_in, const int* in_sizes, int n_in,
                              void* d_out, int out_size, void* d_ws, size_t ws_size,
                              hipStream_t stream) {
    const long M1 = 1048576;
    _Float16* ws = (_Float16*)d_ws;
    _Float16* q16  = ws;             // 2M elts (query; key at +2M, value at +4M)
    _Float16* wq16 = ws + 6 * M1;    // 8M (Wk at +8M, Wv at +16M)
    _Float16* wo16 = ws + 23 * M1;   // 1M
    _Float16* Qbuf = ws + 24 * M1;   // 16M row-major Q (Kbuf at +16M, Vbuf at +32M)
    _Float16* Vbuf = ws + 56 * M1;   // 2M  (== Qbuf + 32M)
    _Float16* Vt   = ws + 58 * M1;   // 2M
    _Float16* Pb   = ws + 60 * M1;   // 16M
    _Float16* Hbar = ws + 76 * M1;   // 2M
    float* out = (float*)d_out;
    float* attn_out = out + 2 * M1;

    // all 7 casts in one dispatch
    cast_all<<<2048, 256, 0, stream>>>(
        (const float*)d_in[0], (const float*)d_in[1], (const float*)d_in[2],
        (const float*)d_in[3], (const float*)d_in[4], (const float*)d_in[5],
        (const float*)d_in[6], ws);

    // Projections, one dispatch (XCD-chunk swizzled flat grid):
    // z=0..7 Q_i = query @ Wq[i]^T; z=8..15 K_i; z=16 V = value @ Wv^T.
    gemm_bt<4, 1, 0><<<2176, 256, 0, stream>>>(
        q16, wq16, Qbuf, 1024, 1024, 1024, 1024,
        /*az*/ 8, 2 * M1, 0, /*sb*/ M1,
        /*cz*/ 16, 32 * M1, 2 * M1);
    // V transpose -> Vt[b][e][s]
    transpose_v<<<dim3(16, 16, 2), 256, 0, stream>>>(Vbuf, Vt);
    // fused scores+softmax+mean_i -> attention (f32) + Pbar (f16)
    attn_fused<<<1024, 512, 0, stream>>>(Qbuf, Qbuf + 16 * M1, attn_out, Pb);
    // PV: head[b][t][h*128+n] = sum_s Pbar[(b,h)][t][s] * Vt[b][h*128+n][s]
    gemm_bt<2, 0, 0><<<dim3(1, 16, 16), 256, 0, stream>>>(
        Pb, Vt, Hbar, 1024, 1024, 1024, 1024,
        /*az*/ 16, 0, M1, /*sb*/ M1 / 8,
        /*cz*/ 8, M1, 128);
    // out = head_mean @ Wo^T  (f32 out)
    gemm_bt<2, 0, 1><<<dim3(8, 32, 1), 256, 0, stream>>>(
        Hbar, wo16, out, 1024, 1024, 1024, 1024,
        1, 0, 0, 0, 1, 0, 0);
}